// Round 1
// baseline (29899.600 us; speedup 1.0000x reference)
//
#include <hip/hip_runtime.h>
#include <math.h>

// Problem constants (fixed by setup_inputs)
constexpr int U      = 128;   // UNITS
constexpr int G4     = 512;   // 4*U gate width
constexpr int NCls   = 10;    // classes
constexpr int TSTEPS = 1000;
constexpr int BATCH  = 256;
constexpr int WH1L   = 64;    // Wh1 rows cached in LDS (128 KB)
// Streamed per step per thread: all Wx1 (128 rows) + Wh1 rows 64..127 (64 rows)
// = 192 dwords = 12 chunks of 16, double-buffered in registers.

__device__ __forceinline__ float sigm(float x) {
    return 1.0f / (1.0f + __expf(-x));
}

// k = time_gate(t, tau, s); floor-mod semantics matching jnp.mod
__device__ __forceinline__ float tgate(float t, float tau, float s) {
    float r = fmodf(t - s, tau);
    if (r < 0.0f) r += tau;
    const float phi = r / tau;
    return (phi < 0.025f) ? 40.0f * phi
         : (phi < 0.05f)  ? 2.0f - 40.0f * phi
         : 0.001f * phi;
}

// Issue 16 streamed weight loads for chunk K into register buffer BUF.
// idx < 128  -> Wx1 row idx;  idx in [128,192) -> Wh1 row (idx-64) (i.e. 64..127)
#define ISSUE(K, BUF) { \
    _Pragma("unroll") \
    for (int ii = 0; ii < 16; ++ii) { \
        const int idx_ = (K) * 16 + ii; \
        (BUF)[ii] = (idx_ < 128) ? wx1p[idx_ * G4] : wh1p[(idx_ - 64) * G4]; \
    } }

// Consume chunk K from BUF. Chunks 0..7: Wx1 rows 16K.. with gh0s broadcast
// (LayerNorm-folded: gh0s[u] = gamma[u]*h0[u]). Chunks 8..11: Wh1 upper rows
// with h1s broadcast.
#define CONSUME(K, BUF) { \
    if ((K) < 8) { \
        _Pragma("unroll") \
        for (int q = 0; q < 4; ++q) { \
            const float4 g4_ = *reinterpret_cast<const float4*>(&gh0s[16*(K) + 4*q]); \
            ax0 += g4_.x * (BUF)[4*q+0]; \
            ax1 += g4_.y * (BUF)[4*q+1]; \
            ax2 += g4_.z * (BUF)[4*q+2]; \
            ax3 += g4_.w * (BUF)[4*q+3]; \
        } \
    } else { \
        _Pragma("unroll") \
        for (int q = 0; q < 4; ++q) { \
            const float4 h4_ = *reinterpret_cast<const float4*>(&h1s[64 + 16*((K)-8) + 4*q]); \
            ah0 += h4_.x * (BUF)[4*q+0]; \
            ah1 += h4_.y * (BUF)[4*q+1]; \
            ah2 += h4_.z * (BUF)[4*q+2]; \
            ah3 += h4_.w * (BUF)[4*q+3]; \
        } \
    } }

__global__ __launch_bounds__(512, 1) void plstm_fused(
    const float* __restrict__ inputs,  // [B,T,3]
    const float* __restrict__ times,   // [B,T]
    const float* __restrict__ Wx0,     // [3,512]
    const float* __restrict__ Wh0,     // [128,512]
    const float* __restrict__ b0,      // [512]
    const float* __restrict__ tau0,    // [128]
    const float* __restrict__ s0,      // [128]
    const float* __restrict__ Wx1,     // [128,512]
    const float* __restrict__ Wh1,     // [128,512]
    const float* __restrict__ b1,      // [512]
    const float* __restrict__ tau1,    // [128]
    const float* __restrict__ s1,      // [128]
    const float* __restrict__ gamma_,  // [128]
    const float* __restrict__ beta_,   // [128]
    const float* __restrict__ Wfc,     // [128,10]
    const float* __restrict__ bfc,     // [10]
    float* __restrict__ out)           // [B,T,10]
{
    const int b = blockIdx.x;
    const int j = threadIdx.x;  // 0..511

    __shared__ __align__(16) float wh1s[WH1L * G4];  // 128 KB: Wh1 rows 0..63
    __shared__ __align__(16) float zs[G4];
    __shared__ __align__(16) float h0s[U];
    __shared__ __align__(16) float gh0s[U];          // gamma[u]*h0[u]
    __shared__ __align__(16) float h1s[U];
    __shared__ __align__(16) float wfcs[U * 11];     // stride 11: no bank aliasing
    __shared__ float bfcs[NCls];
    __shared__ float red[4];                         // {sum0,sq0,sum1,sq1}

    // ---- prologue: stage gamma/beta (temporarily in h0s/h1s), coop loads ----
    if (j < U) { h0s[j] = gamma_[j]; h1s[j] = beta_[j]; }
    {
        const float4* src = reinterpret_cast<const float4*>(Wh1);
        float4*       dst = reinterpret_cast<float4*>(wh1s);
        #pragma unroll
        for (int i = 0; i < (WH1L * G4 / 4) / 512; ++i)   // 16 float4 each
            dst[j + i * 512] = src[j + i * 512];
    }
    for (int i = j; i < U * NCls; i += 512) {
        const int u = i / NCls, c = i - u * NCls;
        wfcs[u * 11 + c] = Wfc[i];
    }
    if (j < NCls) bfcs[j] = bfc[j];
    __syncthreads();

    // ---- LayerNorm fold constants: P[j] = sum_u beta[u]*Wx1[u][j],
    //      Q[j] = sum_u gamma[u]*Wx1[u][j]  (one-time column read) ----
    float Pj = 0.0f, Qj = 0.0f;
    #pragma unroll 8
    for (int u = 0; u < U; ++u) {
        const float w = Wx1[u * G4 + j];
        Qj += h0s[u] * w;   // gamma staged in h0s
        Pj += h1s[u] * w;   // beta  staged in h1s
    }
    __syncthreads();

    if (j < U) { h0s[j] = 0.0f; h1s[j] = 0.0f; gh0s[j] = 0.0f; }

    // ---- per-thread persistent parameters ----
    const float bj0  = b0[j];
    const float bj1  = b1[j];
    const float wx00 = Wx0[j];
    const float wx01 = Wx0[G4 + j];
    const float wx02 = Wx0[2 * G4 + j];
    float tau0r = 0.f, s0r = 0.f, tau1r = 0.f, s1r = 0.f, gr = 0.f;
    if (j < U) {
        tau0r = tau0[j]; s0r = s0[j];
        tau1r = tau1[j]; s1r = s1[j];
        gr = gamma_[j];
    }
    float c0r = 0.f, c1r = 0.f, h0r = 0.f, h1r = 0.f;

    // ---- register-cache the full Wh0 column j (128 VGPRs) ----
    float4 wh0r[32];
    #pragma unroll
    for (int q = 0; q < 32; ++q) {
        wh0r[q].x = Wh0[(4*q+0)*G4 + j];
        wh0r[q].y = Wh0[(4*q+1)*G4 + j];
        wh0r[q].z = Wh0[(4*q+2)*G4 + j];
        wh0r[q].w = Wh0[(4*q+3)*G4 + j];
    }

    const float* __restrict__ xp   = inputs + (size_t)b * TSTEPS * 3;
    const float* __restrict__ tp   = times  + (size_t)b * TSTEPS;
    float*       __restrict__ op   = out    + (size_t)b * TSTEPS * NCls;
    const float* __restrict__ wx1p = Wx1 + j;
    const float* __restrict__ wh1p = Wh1 + j;

    float xa0 = xp[0], xa1 = xp[1], xa2 = xp[2], tva = tp[0];

    __syncthreads();

    for (int t = 0; t < TSTEPS; ++t) {
        const float x0 = xa0, x1 = xa1, x2 = xa2, tv = tva;

        float bufA[16], bufB[16];
        // prefetch first two streamed chunks (consumed after B2) + next x/t
        ISSUE(0, bufA);
        ISSUE(1, bufB);
        const int tn = (t + 1 < TSTEPS) ? t + 1 : t;
        xa0 = xp[tn*3+0]; xa1 = xp[tn*3+1]; xa2 = xp[tn*3+2]; tva = tp[tn];

        // ---- phase A: matvec0 (registers x LDS broadcast), 4 accumulators ----
        float a0 = bj0 + x0 * wx00, a1 = x1 * wx01, a2 = x2 * wx02, a3 = 0.0f;
        #pragma unroll
        for (int q = 0; q < 32; ++q) {
            const float4 h4 = *reinterpret_cast<const float4*>(&h0s[4*q]);
            a0 += h4.x * wh0r[q].x;
            a1 += h4.y * wh0r[q].y;
            a2 += h4.z * wh0r[q].z;
            a3 += h4.w * wh0r[q].w;
        }
        zs[j] = (a0 + a1) + (a2 + a3);
        __syncthreads();                                   // B1

        // ---- phase B: gates0 + LN partial sums (waves 0,1) ----
        if (j < U) {
            const float ig = sigm(zs[j]);
            const float fg = sigm(zs[j + U]);
            const float gg = tanhf(zs[j + 2*U]);
            const float og = sigm(zs[j + 3*U]);
            const float ch = fg * c0r + ig * gg;
            const float hh = og * tanhf(ch);
            const float k  = tgate(tv, tau0r, s0r);
            const float hn = k * hh + (1.0f - k) * h0r;
            c0r = k * ch + (1.0f - k) * c0r;
            h0r = hn;
            h0s[j]  = hn;
            gh0s[j] = gr * hn;
            float ssum = hn, qsum = hn * hn;               // one-pass variance
            #pragma unroll
            for (int off = 1; off < 64; off <<= 1) {
                ssum += __shfl_xor(ssum, off);
                qsum += __shfl_xor(qsum, off);
            }
            if ((j & 63) == 0) { red[(j >> 6)*2] = ssum; red[(j >> 6)*2 + 1] = qsum; }
        }
        __syncthreads();                                   // B2

        // ---- phase C: matvec1 with LN folded in ----
        const float mu   = (red[0] + red[2]) * (1.0f / 128.0f);
        const float msq  = (red[1] + red[3]) * (1.0f / 128.0f);
        const float rstd = rsqrtf(msq - mu * mu + 1e-3f);

        float ax0 = 0.f, ax1 = 0.f, ax2 = 0.f, ax3 = 0.f;  // Swx = sum (g*h0)*Wx1
        float ah0 = 0.f, ah1 = 0.f, ah2 = 0.f, ah3 = 0.f;  // Swh = sum h1*Wh1

        // LDS-cached Wh1 rows 0..63
        #pragma unroll
        for (int q = 0; q < 16; ++q) {
            const float4 h4 = *reinterpret_cast<const float4*>(&h1s[4*q]);
            ah0 += h4.x * wh1s[(4*q+0)*G4 + j];
            ah1 += h4.y * wh1s[(4*q+1)*G4 + j];
            ah2 += h4.z * wh1s[(4*q+2)*G4 + j];
            ah3 += h4.w * wh1s[(4*q+3)*G4 + j];
        }

        // streamed: 12 chunks, 2-deep register double-buffer
        CONSUME(0,  bufA);  ISSUE(2,  bufA);
        CONSUME(1,  bufB);  ISSUE(3,  bufB);
        CONSUME(2,  bufA);  ISSUE(4,  bufA);
        CONSUME(3,  bufB);  ISSUE(5,  bufB);
        CONSUME(4,  bufA);  ISSUE(6,  bufA);
        CONSUME(5,  bufB);  ISSUE(7,  bufB);
        CONSUME(6,  bufA);  ISSUE(8,  bufA);
        CONSUME(7,  bufB);  ISSUE(9,  bufB);
        CONSUME(8,  bufA);  ISSUE(10, bufA);
        CONSUME(9,  bufB);  ISSUE(11, bufB);
        CONSUME(10, bufA);
        CONSUME(11, bufB);

        const float Swx = (ax0 + ax1) + (ax2 + ax3);
        const float Swh = (ah0 + ah1) + (ah2 + ah3);
        // z1 = b1 + P + rstd*Swx - mu*rstd*Q + Swh   (exact LN fold)
        zs[j] = bj1 + Pj + rstd * Swx - (mu * rstd) * Qj + Swh;
        __syncthreads();                                   // B3

        // ---- phase D: gates1 (waves 0,1) ----
        if (j < U) {
            const float ig = sigm(zs[j]);
            const float fg = sigm(zs[j + U]);
            const float gg = tanhf(zs[j + 2*U]);
            const float og = sigm(zs[j + 3*U]);
            const float ch = fg * c1r + ig * gg;
            const float hh = og * tanhf(ch);
            const float k  = tgate(tv, tau1r, s1r);
            const float hn = k * hh + (1.0f - k) * h1r;
            c1r = k * ch + (1.0f - k) * c1r;
            h1r = hn;
            h1s[j] = hn;
        }
        __syncthreads();                                   // B4

        // ---- phase E: FC + softmax (wave 0); other waves roll into t+1 ----
        if (j < 64) {
            const float a  = h1s[j];
            const float bv = h1s[j + 64];
            float p[NCls];
            #pragma unroll
            for (int c = 0; c < NCls; ++c)
                p[c] = a * wfcs[j*11 + c] + bv * wfcs[(j+64)*11 + c];
            #pragma unroll
            for (int off = 1; off < 64; off <<= 1) {
                #pragma unroll
                for (int c = 0; c < NCls; ++c) p[c] += __shfl_xor(p[c], off);
            }
            float m = -1e30f;
            #pragma unroll
            for (int c = 0; c < NCls; ++c) { p[c] += bfcs[c]; m = fmaxf(m, p[c]); }
            float ssum = 0.0f;
            #pragma unroll
            for (int c = 0; c < NCls; ++c) { p[c] = __expf(p[c] - m); ssum += p[c]; }
            const float inv = 1.0f / ssum;
            float pv = p[0];                 // static-index select (no scratch)
            #pragma unroll
            for (int c = 1; c < NCls; ++c) if (j == c) pv = p[c];
            if (j < NCls) op[t * NCls + j] = pv * inv;
        }
    }
}

extern "C" void kernel_launch(void* const* d_in, const int* in_sizes, int n_in,
                              void* d_out, int out_size, void* d_ws, size_t ws_size,
                              hipStream_t stream) {
    const float* inputs = (const float*)d_in[0];
    const float* times  = (const float*)d_in[1];
    const float* Wx0    = (const float*)d_in[2];
    const float* Wh0    = (const float*)d_in[3];
    const float* b0     = (const float*)d_in[4];
    const float* tau0   = (const float*)d_in[5];
    const float* s0     = (const float*)d_in[6];
    const float* Wx1    = (const float*)d_in[7];
    const float* Wh1    = (const float*)d_in[8];
    const float* b1     = (const float*)d_in[9];
    const float* tau1   = (const float*)d_in[10];
    const float* s1     = (const float*)d_in[11];
    const float* gamma_ = (const float*)d_in[12];
    const float* beta_  = (const float*)d_in[13];
    const float* Wfc    = (const float*)d_in[14];
    const float* bfc    = (const float*)d_in[15];
    float* out = (float*)d_out;

    dim3 grid(BATCH);
    dim3 block(512);
    hipLaunchKernelGGL(plstm_fused, grid, block, 0, stream,
                       inputs, times, Wx0, Wh0, b0, tau0, s0,
                       Wx1, Wh1, b1, tau1, s1, gamma_, beta_, Wfc, bfc, out);
}